// Round 8
// baseline (270.173 us; speedup 1.0000x reference)
//
#include <hip/hip_runtime.h>

#define NB 256   // num_basis
#define NO 32    // output_size
#define NI 128   // input_size
// pairs = NB*NO = 8192; Lambda_inv = 512 MB fp32 (streamed once, no reuse)

typedef float f32x4 __attribute__((ext_vector_type(4)));

__device__ __forceinline__ float dot4(f32x4 a, f32x4 b) {
    return fmaf(a.x, b.x, fmaf(a.y, b.y, fmaf(a.z, b.z, a.w * b.w)));
}

// Block-cooperative: the whole 256-thread block streams ONE pair's 64 KB
// Lambda matrix at a time (4 KiB contiguous per step), walking 4 consecutive
// pairs = one contiguous 256 KB stream per block. 2048 streams instead of
// 8192 -> fewer DRAM bank/row collisions between streams.
__global__ __launch_bounds__(256, 8) void rbf_quad_kernel(
    const float* __restrict__ x,        // [NI]
    const float* __restrict__ centers,  // [NB][NO][NI]
    const float* __restrict__ Lam,      // [NB][NO][NI][NI]
    float* __restrict__ rbf)            // [NB*NO]
{
    __shared__ float diff_lds[4][NI];
    __shared__ float part[4][4];        // [wave][pair]
    const int t    = threadIdx.x;
    const int lane = t & 63;
    const int wid  = t >> 6;
    const int p0   = blockIdx.x * 4;

    // Wave w computes diff for pair p0+w -> LDS
    const float2 xv = *(const float2*)(x + 2 * lane);
    const float2 cv = *(const float2*)(centers + (size_t)(p0 + wid) * NI + 2 * lane);
    *(float2*)(&diff_lds[wid][2 * lane]) = make_float2(xv.x - cv.x, xv.y - cv.y);
    __syncthreads();

    const int c4    = t & 31;   // this thread's fixed float4 column block
    const int rbase = t >> 5;   // row offset within each 8-row step (0..7)

    float acc[4];

    #pragma unroll
    for (int q = 0; q < 4; ++q) {
        const f32x4 dj = *(const f32x4*)(&diff_lds[q][4 * c4]);
        const f32x4* __restrict__ Lq =
            (const f32x4*)(Lam + (size_t)(p0 + q) * (NI * NI));
        const float* dl = diff_lds[q];
        float a0 = 0.0f, a1 = 0.0f, a2 = 0.0f, a3 = 0.0f;
        // 16 steps of 256 float4 (8 rows each); unroll 4 -> 4 loads in flight.
        #pragma unroll
        for (int s = 0; s < 16; s += 4) {
            const f32x4 L0 = __builtin_nontemporal_load(Lq + (s + 0) * 256 + t);
            const f32x4 L1 = __builtin_nontemporal_load(Lq + (s + 1) * 256 + t);
            const f32x4 L2 = __builtin_nontemporal_load(Lq + (s + 2) * 256 + t);
            const f32x4 L3 = __builtin_nontemporal_load(Lq + (s + 3) * 256 + t);
            a0 = fmaf(dl[(s + 0) * 8 + rbase], dot4(L0, dj), a0);
            a1 = fmaf(dl[(s + 1) * 8 + rbase], dot4(L1, dj), a1);
            a2 = fmaf(dl[(s + 2) * 8 + rbase], dot4(L2, dj), a2);
            a3 = fmaf(dl[(s + 3) * 8 + rbase], dot4(L3, dj), a3);
        }
        acc[q] = (a0 + a1) + (a2 + a3);
    }

    // Reduce: wave-level shuffle, then cross-wave via LDS.
    #pragma unroll
    for (int q = 0; q < 4; ++q) {
        float v = acc[q];
        #pragma unroll
        for (int off = 32; off; off >>= 1) v += __shfl_xor(v, off);
        if (lane == 0) part[wid][q] = v;
    }
    __syncthreads();

    if (t < 4) {
        const float s_ = part[0][t] + part[1][t] + part[2][t] + part[3][t];
        rbf[p0 + t] = expf(-0.5f * s_);
    }
}

__global__ __launch_bounds__(256) void rbf_policy_kernel(
    const float* __restrict__ weights,  // [NO][NB]
    const float* __restrict__ rbf,      // [NB][NO]  (indexed [b*NO + o])
    const float* __restrict__ bnds,     // [2][NO]
    float* __restrict__ out)            // [NO]
{
    const int o = blockIdx.x;
    const int t = threadIdx.x;          // t == b

    float v = weights[o * NB + t] * rbf[t * NO + o];

    #pragma unroll
    for (int off = 32; off; off >>= 1) v += __shfl_xor(v, off);

    __shared__ float part[4];
    if ((t & 63) == 0) part[t >> 6] = v;
    __syncthreads();

    if (t == 0) {
        const float s   = part[0] + part[1] + part[2] + part[3];
        const float pol = tanhf(s);
        const float lo  = bnds[o];
        const float hi  = bnds[NO + o];
        out[o] = (pol + 1.0f) * 0.5f * (hi - lo) + lo;
    }
}

extern "C" void kernel_launch(void* const* d_in, const int* in_sizes, int n_in,
                              void* d_out, int out_size, void* d_ws, size_t ws_size,
                              hipStream_t stream) {
    const float* x       = (const float*)d_in[0];
    const float* weights = (const float*)d_in[1];
    const float* centers = (const float*)d_in[2];
    const float* Lam     = (const float*)d_in[3];
    const float* bnds    = (const float*)d_in[4];
    float* out = (float*)d_out;
    float* rbf = (float*)d_ws;   // NB*NO floats = 32 KB

    rbf_quad_kernel<<<2048, 256, 0, stream>>>(x, centers, Lam, rbf);
    rbf_policy_kernel<<<NO, NB, 0, stream>>>(weights, rbf, bnds, out);
}

// Round 9
// 87.122 us; speedup vs baseline: 3.1011x; 3.1011x over previous
//
#include <hip/hip_runtime.h>

#define NB 256   // num_basis
#define NO 32    // output_size
#define NI 128   // input_size
// pairs = NB*NO = 8192; Lambda_inv = 512 MB fp32

typedef float f32x4 __attribute__((ext_vector_type(4)));

__global__ __launch_bounds__(256, 4) void rbf_quad_kernel(
    const float* __restrict__ x,        // [NI]
    const float* __restrict__ centers,  // [NB][NO][NI]
    const float* __restrict__ Lam,      // [NB][NO][NI][NI]
    float* __restrict__ rbf)            // [NB*NO]
{
    __shared__ float diff_lds[4][NI];
    const int lane = threadIdx.x & 63;
    const int wid  = threadIdx.x >> 6;
    const int p    = blockIdx.x * 4 + wid;   // pair index = b*NO + o

    // diff = x - centers[p], 2 elements per lane -> LDS
    const float2 xv = *(const float2*)(x + 2 * lane);
    const float2 cv = *(const float2*)(centers + (size_t)p * NI + 2 * lane);
    *(float2*)(&diff_lds[wid][2 * lane]) = make_float2(xv.x - cv.x, xv.y - cv.y);
    __syncthreads();

    // Lane owns columns c..c+3 (held in dj); half-wave h picks the row
    // within each 2-row slab.
    const int c = 4 * (lane & 31);
    const int h = lane >> 5;
    const f32x4 dj = *(const f32x4*)(&diff_lds[wid][c]);

    const f32x4* __restrict__ Lq = (const f32x4*)(Lam + (size_t)p * (NI * NI));
    float acc0 = 0.0f, acc1 = 0.0f;

    // Per iteration: 2 KiB/wave = rows 4it..4it+3.
    //   L0 (rows 4it,4it+1)   : NORMAL load
    //   L1 (rows 4it+2,4it+3) : NONTEMPORAL
    // (R4 config — best measured of 6 variants; the nt/normal mix with two
    //  independent chains at the 128-VGPR budget sustains ~6.2 TB/s read.)
    #pragma unroll 8
    for (int it = 0; it < NI / 4; ++it) {
        const f32x4 L0 = Lq[(size_t)it * 128 + lane];
        const f32x4 L1 = __builtin_nontemporal_load(Lq + (size_t)it * 128 + 64 + lane);
        const float di0 = diff_lds[wid][4 * it + h];
        const float di1 = diff_lds[wid][4 * it + 2 + h];
        acc0 = fmaf(di0,
                    fmaf(L0.x, dj.x, fmaf(L0.y, dj.y, fmaf(L0.z, dj.z, L0.w * dj.w))),
                    acc0);
        acc1 = fmaf(di1,
                    fmaf(L1.x, dj.x, fmaf(L1.y, dj.y, fmaf(L1.z, dj.z, L1.w * dj.w))),
                    acc1);
    }

    float acc = acc0 + acc1;
    #pragma unroll
    for (int off = 32; off; off >>= 1) acc += __shfl_xor(acc, off);

    if (lane == 0) rbf[p] = expf(-0.5f * acc);
}

__global__ __launch_bounds__(256) void rbf_policy_kernel(
    const float* __restrict__ weights,  // [NO][NB]
    const float* __restrict__ rbf,      // [NB][NO]  (indexed [b*NO + o])
    const float* __restrict__ bnds,     // [2][NO]
    float* __restrict__ out)            // [NO]
{
    const int o = blockIdx.x;
    const int t = threadIdx.x;          // t == b

    float v = weights[o * NB + t] * rbf[t * NO + o];

    #pragma unroll
    for (int off = 32; off; off >>= 1) v += __shfl_xor(v, off);

    __shared__ float part[4];
    if ((t & 63) == 0) part[t >> 6] = v;
    __syncthreads();

    if (t == 0) {
        const float s   = part[0] + part[1] + part[2] + part[3];
        const float pol = tanhf(s);
        const float lo  = bnds[o];
        const float hi  = bnds[NO + o];
        out[o] = (pol + 1.0f) * 0.5f * (hi - lo) + lo;
    }
}

extern "C" void kernel_launch(void* const* d_in, const int* in_sizes, int n_in,
                              void* d_out, int out_size, void* d_ws, size_t ws_size,
                              hipStream_t stream) {
    const float* x       = (const float*)d_in[0];
    const float* weights = (const float*)d_in[1];
    const float* centers = (const float*)d_in[2];
    const float* Lam     = (const float*)d_in[3];
    const float* bnds    = (const float*)d_in[4];
    float* out = (float*)d_out;
    float* rbf = (float*)d_ws;   // NB*NO floats = 32 KB

    rbf_quad_kernel<<<2048, 256, 0, stream>>>(x, centers, Lam, rbf);
    rbf_policy_kernel<<<NO, NB, 0, stream>>>(weights, rbf, bnds, out);
}